// Round 11
// baseline (532.245 us; speedup 1.0000x reference)
//
#include <hip/hip_runtime.h>
#include <hip/hip_fp16.h>

// ---------------- preprocessing: histogram+rank, 3-phase scan (+dinv), passed scatter ----

__global__ void hist_rank_kernel(const int* __restrict__ dst, int E, int* __restrict__ count,
                                 int* __restrict__ rank) {
    int stride = gridDim.x * blockDim.x;
    int t = blockIdx.x * blockDim.x + threadIdx.x;
    int E4 = E >> 2;
    for (int e = t; e < E4; e += stride) {
        int4 d = ((const int4*)dst)[e];
        int4 r;
        r.x = atomicAdd(&count[d.x], 1);
        r.y = atomicAdd(&count[d.y], 1);
        r.z = atomicAdd(&count[d.z], 1);
        r.w = atomicAdd(&count[d.w], 1);
        ((int4*)rank)[e] = r;
    }
    for (int e = (E4 << 2) + t; e < E; e += stride) rank[e] = atomicAdd(&count[dst[e]], 1);
}

__global__ void scan_partial_kernel(const int* __restrict__ count, int* __restrict__ partials,
                                    int N) {
    __shared__ int red[4];
    int t = threadIdx.x;
    int idx = blockIdx.x * 1024 + t * 4;
    int s = 0;
    if (idx + 3 < N) {
        int4 c = *(const int4*)(count + idx);
        s = c.x + c.y + c.z + c.w;
    } else {
#pragma unroll
        for (int k = 0; k < 4; ++k)
            if (idx + k < N) s += count[idx + k];
    }
#pragma unroll
    for (int off = 1; off < 64; off <<= 1) s += __shfl_xor(s, off);
    if ((t & 63) == 0) red[t >> 6] = s;
    __syncthreads();
    if (t == 0) partials[blockIdx.x] = red[0] + red[1] + red[2] + red[3];
}

__global__ void scan_top_kernel(int* __restrict__ partials, int nb, int* __restrict__ row_ptr,
                                int N) {
    __shared__ int buf[2][128];
    int t = threadIdx.x;
    buf[0][t] = (t < nb) ? partials[t] : 0;
    __syncthreads();
    int pi = 0;
    for (int off = 1; off < 128; off <<= 1) {
        int v = buf[pi][t];
        if (t >= off) v += buf[pi][t - off];
        buf[pi ^ 1][t] = v;
        pi ^= 1;
        __syncthreads();
    }
    if (t < nb) partials[t] = (t == 0) ? 0 : buf[pi][t - 1];
    if (t == 0) row_ptr[N] = buf[pi][127];
}

__global__ void scan_apply_kernel(const int* __restrict__ count, const int* __restrict__ partials,
                                  int* __restrict__ row_ptr, float* __restrict__ dinv, int N) {
    __shared__ int wsum[4];
    int t = threadIdx.x;
    int idx = blockIdx.x * 1024 + t * 4;
    int4 c = make_int4(0, 0, 0, 0);
    if (idx + 3 < N) {
        c = *(const int4*)(count + idx);
    } else {
        if (idx + 0 < N) c.x = count[idx + 0];
        if (idx + 1 < N) c.y = count[idx + 1];
        if (idx + 2 < N) c.z = count[idx + 2];
    }
    int s = c.x + c.y + c.z + c.w;
    int incl = s;
#pragma unroll
    for (int off = 1; off < 64; off <<= 1) {
        int v = __shfl_up(incl, off);
        if ((t & 63) >= off) incl += v;
    }
    int wexcl = incl - s;
    int w = t >> 6;
    if ((t & 63) == 63) wsum[w] = incl;
    __syncthreads();
    int base = partials[blockIdx.x] + wexcl;
    for (int k = 0; k < w; ++k) base += wsum[k];
    if (idx + 0 < N) { row_ptr[idx + 0] = base;                   dinv[idx + 0] = rsqrtf((float)c.x + 1.f); }
    if (idx + 1 < N) { row_ptr[idx + 1] = base + c.x;             dinv[idx + 1] = rsqrtf((float)c.y + 1.f); }
    if (idx + 2 < N) { row_ptr[idx + 2] = base + c.x + c.y;       dinv[idx + 2] = rsqrtf((float)c.z + 1.f); }
    if (idx + 3 < N) { row_ptr[idx + 3] = base + c.x + c.y + c.z; dinv[idx + 3] = rsqrtf((float)c.w + 1.f); }
}

// atomic-free scatter with dst-range write blocking (pass p writes only a ~E/NPASS window)
#define NPASS 4
__global__ void scatter_kernel(const int* __restrict__ src, const int* __restrict__ dst,
                               const int* __restrict__ rank, int E,
                               const int* __restrict__ row_ptr, int* __restrict__ col, int N) {
    int chunk = (N + NPASS - 1) / NPASS;
    int stride = gridDim.x * blockDim.x;
    int t = blockIdx.x * blockDim.x + threadIdx.x;
    int E4 = E >> 2;
    for (int pass = 0; pass < NPASS; ++pass) {
        int lo = pass * chunk, hi = min(lo + chunk, N);
        for (int e = t; e < E4; e += stride) {
            int4 d = ((const int4*)dst)[e];
            int4 s = ((const int4*)src)[e];
            int4 r = ((const int4*)rank)[e];
            if (d.x >= lo && d.x < hi) col[row_ptr[d.x] + r.x] = s.x;
            if (d.y >= lo && d.y < hi) col[row_ptr[d.y] + r.y] = s.y;
            if (d.z >= lo && d.z < hi) col[row_ptr[d.z] + r.z] = s.z;
            if (d.w >= lo && d.w < hi) col[row_ptr[d.w] + r.w] = s.w;
        }
        for (int e = (E4 << 2) + t; e < E; e += stride) {
            int d = dst[e];
            if (d >= lo && d < hi) col[row_ptr[d] + rank[e]] = src[e];
        }
    }
}

// -------- fp32 GEMM, PRE-SCALED fp16 output: Out[r] = dinv[r] * (A @ W)[r] --------------

__global__ __launch_bounds__(256, 2) void gemm_kernel(const float* __restrict__ A,
                                                      const float* __restrict__ W,
                                                      const float* __restrict__ dinv,
                                                      __half* __restrict__ Out, int M) {
    const int K = 128;
    __shared__ float Ws[K][64];
    __shared__ float As[64][68];
    int t = threadIdx.x;
    for (int i = t * 4; i < K * 64; i += 1024)
        *(float4*)&Ws[i >> 6][i & 63] = *(const float4*)(W + i);

    int row0 = blockIdx.x * 64;
    int rt = (t >> 4) * 4;
    int ct = (t & 15) * 4;
    float acc[4][4];
#pragma unroll
    for (int m = 0; m < 4; m++) { acc[m][0] = 0.f; acc[m][1] = 0.f; acc[m][2] = 0.f; acc[m][3] = 0.f; }

    for (int k0 = 0; k0 < K; k0 += 64) {
        __syncthreads();
        for (int i = t * 4; i < 64 * 64; i += 1024) {
            int r = i >> 6, c = i & 63;
            int gr = row0 + r;
            float4 v = make_float4(0.f, 0.f, 0.f, 0.f);
            if (gr < M) v = *(const float4*)(A + (size_t)gr * K + k0 + c);
            *(float4*)&As[r][c] = v;
        }
        __syncthreads();
#pragma unroll
        for (int kk = 0; kk < 64; ++kk) {
            float a0 = As[rt + 0][kk], a1 = As[rt + 1][kk];
            float a2 = As[rt + 2][kk], a3 = As[rt + 3][kk];
            float4 w = *(float4*)&Ws[k0 + kk][ct];
            acc[0][0] += a0 * w.x; acc[0][1] += a0 * w.y; acc[0][2] += a0 * w.z; acc[0][3] += a0 * w.w;
            acc[1][0] += a1 * w.x; acc[1][1] += a1 * w.y; acc[1][2] += a1 * w.z; acc[1][3] += a1 * w.w;
            acc[2][0] += a2 * w.x; acc[2][1] += a2 * w.y; acc[2][2] += a2 * w.z; acc[2][3] += a2 * w.w;
            acc[3][0] += a3 * w.x; acc[3][1] += a3 * w.y; acc[3][2] += a3 * w.z; acc[3][3] += a3 * w.w;
        }
    }
#pragma unroll
    for (int m = 0; m < 4; m++) {
        int gr = row0 + rt + m;
        if (gr < M) {
            float dv = dinv[gr];
            union { uint2 u; __half h[4]; } pk;
            pk.h[0] = __float2half(dv * acc[m][0]);
            pk.h[1] = __float2half(dv * acc[m][1]);
            pk.h[2] = __float2half(dv * acc[m][2]);
            pk.h[3] = __float2half(dv * acc[m][3]);
            *(uint2*)(Out + (size_t)gr * 64 + ct) = pk.u;
        }
    }
}

// -------- pipelined edge-aggregation core (pre-scaled fp16 payload) ---------------------
// wave = 4 groups x 16 lanes; lane l covers channels 4(l&15)..+3.

__device__ __forceinline__ float4 agg_body(const __half* __restrict__ Hin,
                                           const int* __restrict__ col,
                                           const int* pc, int beg, int end,
                                           int i, int g, int l) {
    float4 acc = make_float4(0.f, 0.f, 0.f, 0.f);
    if (g == 0) {  // self-loop (pre-scaled: h'_i)
        union { uint2 u; __half h[4]; } v;
        v.u = *(const uint2*)(Hin + (size_t)i * 64 + l * 4);
        acc.x = __half2float(v.h[0]); acc.y = __half2float(v.h[1]);
        acc.z = __half2float(v.h[2]); acc.w = __half2float(v.h[3]);
    }
    {   // round A: prefetched cols, predicated by weight
        float w[4];
        uint2 vv[4];
#pragma unroll
        for (int k = 0; k < 4; ++k) {
            w[k] = (beg + g + 4 * k < end) ? 1.f : 0.f;
            vv[k] = *(const uint2*)(Hin + (size_t)pc[k] * 64 + l * 4);
        }
#pragma unroll
        for (int k = 0; k < 4; ++k) {
            union { uint2 u; __half h[4]; } v;
            v.u = vv[k];
            acc.x = fmaf(w[k], __half2float(v.h[0]), acc.x);
            acc.y = fmaf(w[k], __half2float(v.h[1]), acc.y);
            acc.z = fmaf(w[k], __half2float(v.h[2]), acc.z);
            acc.w = fmaf(w[k], __half2float(v.h[3]), acc.w);
        }
    }
    // overflow (deg>16): dynamic rounds
    int e = beg + 16;
    for (; e + 16 <= end; e += 16) {
        int s[4];
#pragma unroll
        for (int k = 0; k < 4; ++k) s[k] = col[e + g + 4 * k];
        uint2 vv[4];
#pragma unroll
        for (int k = 0; k < 4; ++k) vv[k] = *(const uint2*)(Hin + (size_t)s[k] * 64 + l * 4);
#pragma unroll
        for (int k = 0; k < 4; ++k) {
            union { uint2 u; __half h[4]; } v;
            v.u = vv[k];
            acc.x += __half2float(v.h[0]); acc.y += __half2float(v.h[1]);
            acc.z += __half2float(v.h[2]); acc.w += __half2float(v.h[3]);
        }
    }
    if (e < end) {
        float w[4];
        uint2 vv[4];
#pragma unroll
        for (int k = 0; k < 4; ++k) {
            int ie = e + g + 4 * k;
            int s = (ie < end) ? col[ie] : 0;
            w[k] = (ie < end) ? 1.f : 0.f;
            vv[k] = *(const uint2*)(Hin + (size_t)s * 64 + l * 4);
        }
#pragma unroll
        for (int k = 0; k < 4; ++k) {
            union { uint2 u; __half h[4]; } v;
            v.u = vv[k];
            acc.x = fmaf(w[k], __half2float(v.h[0]), acc.x);
            acc.y = fmaf(w[k], __half2float(v.h[1]), acc.y);
            acc.z = fmaf(w[k], __half2float(v.h[2]), acc.z);
            acc.w = fmaf(w[k], __half2float(v.h[3]), acc.w);
        }
    }
    acc.x += __shfl_xor(acc.x, 16); acc.y += __shfl_xor(acc.y, 16);
    acc.z += __shfl_xor(acc.z, 16); acc.w += __shfl_xor(acc.w, 16);
    acc.x += __shfl_xor(acc.x, 32); acc.y += __shfl_xor(acc.y, 32);
    acc.z += __shfl_xor(acc.z, 32); acc.w += __shfl_xor(acc.w, 32);
    return acc;
}

// layer 1: t = relu(agg + b0); store pre-scaled h' = dinv_i * t   (fp16)
__global__ __launch_bounds__(256, 8) void agg_relu_kernel(
        const __half* __restrict__ Hin, const int* __restrict__ row_ptr,
        const int* __restrict__ col, const float* __restrict__ dinv,
        const float* __restrict__ bias, __half* __restrict__ Hout, int N) {
    int t = threadIdx.x;
    int lane = t & 63;
    int g = lane >> 4, l = lane & 15;
    int gw = (blockIdx.x * blockDim.x + t) >> 6;
    int TW = (gridDim.x * blockDim.x) >> 6;

    float4 b4 = (l < 16) ? *(const float4*)(bias + l * 4) : make_float4(0, 0, 0, 0);

    int i = gw;
    int beg = 0, end = 0, pc0 = 0, pc1 = 0, pc2 = 0, pc3 = 0;
    if (i < N) {
        beg = row_ptr[i]; end = row_ptr[i + 1];
        pc0 = (beg + g      < end) ? col[beg + g]      : 0;
        pc1 = (beg + g + 4  < end) ? col[beg + g + 4]  : 0;
        pc2 = (beg + g + 8  < end) ? col[beg + g + 8]  : 0;
        pc3 = (beg + g + 12 < end) ? col[beg + g + 12] : 0;
    }
    while (i < N) {
        int inext = i + TW;
        int beg_n = 0, end_n = 0;
        if (inext < N) { beg_n = row_ptr[inext]; end_n = row_ptr[inext + 1]; }

        int pc[4] = {pc0, pc1, pc2, pc3};
        float di = dinv[i];
        float4 r = agg_body(Hin, col, pc, beg, end, i, g, l);

        if (inext < N) {
            pc0 = (beg_n + g      < end_n) ? col[beg_n + g]      : 0;
            pc1 = (beg_n + g + 4  < end_n) ? col[beg_n + g + 4]  : 0;
            pc2 = (beg_n + g + 8  < end_n) ? col[beg_n + g + 8]  : 0;
            pc3 = (beg_n + g + 12 < end_n) ? col[beg_n + g + 12] : 0;
        }

        if (lane < 16) {
            union { uint2 u; __half h[4]; } pk;
            pk.h[0] = __float2half(di * fmaxf(di * r.x + b4.x, 0.f));
            pk.h[1] = __float2half(di * fmaxf(di * r.y + b4.y, 0.f));
            pk.h[2] = __float2half(di * fmaxf(di * r.z + b4.z, 0.f));
            pk.h[3] = __float2half(di * fmaxf(di * r.w + b4.w, 0.f));
            *(uint2*)(Hout + (size_t)i * 64 + l * 4) = pk.u;
        }
        beg = beg_n; end = end_n; i = inext;
    }
}

// layer 2 FUSED: g = agg(h); out = [ g@Wm + bm | g@Wl + bl ]  (agg(h@W) == agg(h)@W)
__global__ __launch_bounds__(256, 8) void agg_out_fused_kernel(
        const __half* __restrict__ Hin, const int* __restrict__ row_ptr,
        const int* __restrict__ col, const float* __restrict__ dinv,
        const float* __restrict__ Wm, const float* __restrict__ Wl,
        const float* __restrict__ bm, const float* __restrict__ bl,
        float* __restrict__ out, int N) {
    __shared__ float Ws[64][64];
    int t = threadIdx.x;
    for (int i = t * 4; i < 64 * 32; i += 1024) {
        int k = i >> 5, c = i & 31;
        *(float4*)&Ws[k][c]      = *(const float4*)(Wm + i);
        *(float4*)&Ws[k][32 + c] = *(const float4*)(Wl + i);
    }
    __syncthreads();

    int lane = t & 63;
    int g = lane >> 4, l = lane & 15;
    float bj = (lane < 32) ? bm[lane] : bl[lane - 32];

    int gw = (blockIdx.x * blockDim.x + t) >> 6;
    int TW = (gridDim.x * blockDim.x) >> 6;

    int i = gw;
    int beg = 0, end = 0, pc0 = 0, pc1 = 0, pc2 = 0, pc3 = 0;
    if (i < N) {
        beg = row_ptr[i]; end = row_ptr[i + 1];
        pc0 = (beg + g      < end) ? col[beg + g]      : 0;
        pc1 = (beg + g + 4  < end) ? col[beg + g + 4]  : 0;
        pc2 = (beg + g + 8  < end) ? col[beg + g + 8]  : 0;
        pc3 = (beg + g + 12 < end) ? col[beg + g + 12] : 0;
    }
    while (i < N) {
        int inext = i + TW;
        int beg_n = 0, end_n = 0;
        if (inext < N) { beg_n = row_ptr[inext]; end_n = row_ptr[inext + 1]; }

        int pc[4] = {pc0, pc1, pc2, pc3};
        float di = dinv[i];
        float4 r = agg_body(Hin, col, pc, beg, end, i, g, l);

        if (inext < N) {
            pc0 = (beg_n + g      < end_n) ? col[beg_n + g]      : 0;
            pc1 = (beg_n + g + 4  < end_n) ? col[beg_n + g + 4]  : 0;
            pc2 = (beg_n + g + 8  < end_n) ? col[beg_n + g + 8]  : 0;
            pc3 = (beg_n + g + 12 < end_n) ? col[beg_n + g + 12] : 0;
        }

        float a[4] = {di * r.x, di * r.y, di * r.z, di * r.w};
        float o0 = bj, o1 = 0.f, o2 = 0.f, o3 = 0.f;
#pragma unroll
        for (int k = 0; k < 64; k += 4) {
            int srcl = k >> 2;
            o0 = fmaf(__shfl(a[0], srcl, 64), Ws[k + 0][lane], o0);
            o1 = fmaf(__shfl(a[1], srcl, 64), Ws[k + 1][lane], o1);
            o2 = fmaf(__shfl(a[2], srcl, 64), Ws[k + 2][lane], o2);
            o3 = fmaf(__shfl(a[3], srcl, 64), Ws[k + 3][lane], o3);
        }
        float o = (o0 + o1) + (o2 + o3);
        if (lane < 32) out[(size_t)i * 32 + lane] = o;
        else           out[(size_t)(N + i) * 32 + (lane - 32)] = o;

        beg = beg_n; end = end_n; i = inext;
    }
}

// ---------------- launch ----------------

extern "C" void kernel_launch(void* const* d_in, const int* in_sizes, int n_in,
                              void* d_out, int out_size, void* d_ws, size_t ws_size,
                              hipStream_t stream) {
    const float* x  = (const float*)d_in[0];
    const int*   ei = (const int*)d_in[1];   // int32 (JAX default int)
    const float* W0 = (const float*)d_in[2];
    const float* b0 = (const float*)d_in[3];
    const float* Wm = (const float*)d_in[4];
    const float* bm = (const float*)d_in[5];
    const float* Wl = (const float*)d_in[6];
    const float* bl = (const float*)d_in[7];
    float* out = (float*)d_out;

    int N = in_sizes[0] / 128;
    int E = in_sizes[1] / 2;
    const int* src = ei;
    const int* dst = ei + E;

    char* p = (char*)d_ws;
    auto carve = [&](size_t bytes) -> void* {
        void* q = (void*)p;
        p += (bytes + 255) & ~(size_t)255;
        return q;
    };
    int*    count    = (int*)carve((size_t)N * 4);
    int*    row_ptr  = (int*)carve(((size_t)N + 1) * 4);
    int*    col      = (int*)carve((size_t)E * 4);
    int*    rank     = (int*)carve((size_t)E * 4);
    float*  dinv     = (float*)carve((size_t)N * 4);
    int*    partials = (int*)carve(128 * 4);
    __half* h0       = (__half*)carve((size_t)N * 64 * 2);  // dinv*(x@W0) (fp16)
    __half* h        = (__half*)carve((size_t)N * 64 * 2);  // dinv*relu'd hidden (fp16)

    int nb = (N + 1023) / 1024;  // scan blocks (<=128 for N<=131072)

    hipMemsetAsync(count, 0, (size_t)N * 4, stream);
    hist_rank_kernel<<<2048, 256, 0, stream>>>(dst, E, count, rank);
    scan_partial_kernel<<<nb, 256, 0, stream>>>(count, partials, N);
    scan_top_kernel<<<1, 128, 0, stream>>>(partials, nb, row_ptr, N);
    scan_apply_kernel<<<nb, 256, 0, stream>>>(count, partials, row_ptr, dinv, N);
    scatter_kernel<<<2048, 256, 0, stream>>>(src, dst, rank, E, row_ptr, col, N);

    // layer 0: h0' = dinv * (x @ W0) ; h' = dinv * relu(agg(h0') + b0)
    gemm_kernel<<<(N + 63) / 64, 256, 0, stream>>>(x, W0, dinv, h0, N);
    agg_relu_kernel<<<4096, 256, 0, stream>>>(h0, row_ptr, col, dinv, b0, h, N);

    // layer 2 fused: out = [agg(h')@Wm + bm | agg(h')@Wl + bl]
    agg_out_fused_kernel<<<4096, 256, 0, stream>>>(h, row_ptr, col, dinv, Wm, Wl, bm, bl, out, N);
}

// Round 12
// 370.831 us; speedup vs baseline: 1.4353x; 1.4353x over previous
//
#include <hip/hip_runtime.h>
#include <hip/hip_fp16.h>

// ---------------- preprocessing: histogram+rank, 3-phase scan (+dinv), passed scatter ----

__global__ void hist_rank_kernel(const int* __restrict__ dst, int E, int* __restrict__ count,
                                 int* __restrict__ rank) {
    int stride = gridDim.x * blockDim.x;
    int t = blockIdx.x * blockDim.x + threadIdx.x;
    int E4 = E >> 2;
    for (int e = t; e < E4; e += stride) {
        int4 d = ((const int4*)dst)[e];
        int4 r;
        r.x = atomicAdd(&count[d.x], 1);
        r.y = atomicAdd(&count[d.y], 1);
        r.z = atomicAdd(&count[d.z], 1);
        r.w = atomicAdd(&count[d.w], 1);
        ((int4*)rank)[e] = r;
    }
    for (int e = (E4 << 2) + t; e < E; e += stride) rank[e] = atomicAdd(&count[dst[e]], 1);
}

__global__ void scan_partial_kernel(const int* __restrict__ count, int* __restrict__ partials,
                                    int N) {
    __shared__ int red[4];
    int t = threadIdx.x;
    int idx = blockIdx.x * 1024 + t * 4;
    int s = 0;
    if (idx + 3 < N) {
        int4 c = *(const int4*)(count + idx);
        s = c.x + c.y + c.z + c.w;
    } else {
#pragma unroll
        for (int k = 0; k < 4; ++k)
            if (idx + k < N) s += count[idx + k];
    }
#pragma unroll
    for (int off = 1; off < 64; off <<= 1) s += __shfl_xor(s, off);
    if ((t & 63) == 0) red[t >> 6] = s;
    __syncthreads();
    if (t == 0) partials[blockIdx.x] = red[0] + red[1] + red[2] + red[3];
}

__global__ void scan_top_kernel(int* __restrict__ partials, int nb, int* __restrict__ row_ptr,
                                int N) {
    __shared__ int buf[2][128];
    int t = threadIdx.x;
    buf[0][t] = (t < nb) ? partials[t] : 0;
    __syncthreads();
    int pi = 0;
    for (int off = 1; off < 128; off <<= 1) {
        int v = buf[pi][t];
        if (t >= off) v += buf[pi][t - off];
        buf[pi ^ 1][t] = v;
        pi ^= 1;
        __syncthreads();
    }
    if (t < nb) partials[t] = (t == 0) ? 0 : buf[pi][t - 1];
    if (t == 0) row_ptr[N] = buf[pi][127];
}

__global__ void scan_apply_kernel(const int* __restrict__ count, const int* __restrict__ partials,
                                  int* __restrict__ row_ptr, float* __restrict__ dinv, int N) {
    __shared__ int wsum[4];
    int t = threadIdx.x;
    int idx = blockIdx.x * 1024 + t * 4;
    int4 c = make_int4(0, 0, 0, 0);
    if (idx + 3 < N) {
        c = *(const int4*)(count + idx);
    } else {
        if (idx + 0 < N) c.x = count[idx + 0];
        if (idx + 1 < N) c.y = count[idx + 1];
        if (idx + 2 < N) c.z = count[idx + 2];
    }
    int s = c.x + c.y + c.z + c.w;
    int incl = s;
#pragma unroll
    for (int off = 1; off < 64; off <<= 1) {
        int v = __shfl_up(incl, off);
        if ((t & 63) >= off) incl += v;
    }
    int wexcl = incl - s;
    int w = t >> 6;
    if ((t & 63) == 63) wsum[w] = incl;
    __syncthreads();
    int base = partials[blockIdx.x] + wexcl;
    for (int k = 0; k < w; ++k) base += wsum[k];
    if (idx + 0 < N) { row_ptr[idx + 0] = base;                   dinv[idx + 0] = rsqrtf((float)c.x + 1.f); }
    if (idx + 1 < N) { row_ptr[idx + 1] = base + c.x;             dinv[idx + 1] = rsqrtf((float)c.y + 1.f); }
    if (idx + 2 < N) { row_ptr[idx + 2] = base + c.x + c.y;       dinv[idx + 2] = rsqrtf((float)c.z + 1.f); }
    if (idx + 3 < N) { row_ptr[idx + 3] = base + c.x + c.y + c.z; dinv[idx + 3] = rsqrtf((float)c.w + 1.f); }
}

// atomic-free scatter with dst-range write blocking (pass p writes only a ~N/NPASS window)
#define NPASS 8
__global__ void scatter_kernel(const int* __restrict__ src, const int* __restrict__ dst,
                               const int* __restrict__ rank, int E,
                               const int* __restrict__ row_ptr, int* __restrict__ col, int N) {
    int chunk = (N + NPASS - 1) / NPASS;
    int stride = gridDim.x * blockDim.x;
    int t = blockIdx.x * blockDim.x + threadIdx.x;
    int E4 = E >> 2;
    for (int pass = 0; pass < NPASS; ++pass) {
        int lo = pass * chunk, hi = min(lo + chunk, N);
        for (int e = t; e < E4; e += stride) {
            int4 d = ((const int4*)dst)[e];
            int4 s = ((const int4*)src)[e];
            int4 r = ((const int4*)rank)[e];
            if (d.x >= lo && d.x < hi) col[row_ptr[d.x] + r.x] = s.x;
            if (d.y >= lo && d.y < hi) col[row_ptr[d.y] + r.y] = s.y;
            if (d.z >= lo && d.z < hi) col[row_ptr[d.z] + r.z] = s.z;
            if (d.w >= lo && d.w < hi) col[row_ptr[d.w] + r.w] = s.w;
        }
        for (int e = (E4 << 2) + t; e < E; e += stride) {
            int d = dst[e];
            if (d >= lo && d < hi) col[row_ptr[d] + rank[e]] = src[e];
        }
    }
}

// -------- fp32 GEMM, PRE-SCALED fp16 output: Out[r] = dinv[r] * (A @ W)[r] --------------

__global__ __launch_bounds__(256, 2) void gemm_kernel(const float* __restrict__ A,
                                                      const float* __restrict__ W,
                                                      const float* __restrict__ dinv,
                                                      __half* __restrict__ Out, int M) {
    const int K = 128;
    __shared__ float Ws[K][64];
    __shared__ float As[64][68];
    int t = threadIdx.x;
    for (int i = t * 4; i < K * 64; i += 1024)
        *(float4*)&Ws[i >> 6][i & 63] = *(const float4*)(W + i);

    int row0 = blockIdx.x * 64;
    int rt = (t >> 4) * 4;
    int ct = (t & 15) * 4;
    float acc[4][4];
#pragma unroll
    for (int m = 0; m < 4; m++) { acc[m][0] = 0.f; acc[m][1] = 0.f; acc[m][2] = 0.f; acc[m][3] = 0.f; }

    for (int k0 = 0; k0 < K; k0 += 64) {
        __syncthreads();
        for (int i = t * 4; i < 64 * 64; i += 1024) {
            int r = i >> 6, c = i & 63;
            int gr = row0 + r;
            float4 v = make_float4(0.f, 0.f, 0.f, 0.f);
            if (gr < M) v = *(const float4*)(A + (size_t)gr * K + k0 + c);
            *(float4*)&As[r][c] = v;
        }
        __syncthreads();
#pragma unroll
        for (int kk = 0; kk < 64; ++kk) {
            float a0 = As[rt + 0][kk], a1 = As[rt + 1][kk];
            float a2 = As[rt + 2][kk], a3 = As[rt + 3][kk];
            float4 w = *(float4*)&Ws[k0 + kk][ct];
            acc[0][0] += a0 * w.x; acc[0][1] += a0 * w.y; acc[0][2] += a0 * w.z; acc[0][3] += a0 * w.w;
            acc[1][0] += a1 * w.x; acc[1][1] += a1 * w.y; acc[1][2] += a1 * w.z; acc[1][3] += a1 * w.w;
            acc[2][0] += a2 * w.x; acc[2][1] += a2 * w.y; acc[2][2] += a2 * w.z; acc[2][3] += a2 * w.w;
            acc[3][0] += a3 * w.x; acc[3][1] += a3 * w.y; acc[3][2] += a3 * w.z; acc[3][3] += a3 * w.w;
        }
    }
#pragma unroll
    for (int m = 0; m < 4; m++) {
        int gr = row0 + rt + m;
        if (gr < M) {
            float dv = dinv[gr];
            union { uint2 u; __half h[4]; } pk;
            pk.h[0] = __float2half(dv * acc[m][0]);
            pk.h[1] = __float2half(dv * acc[m][1]);
            pk.h[2] = __float2half(dv * acc[m][2]);
            pk.h[3] = __float2half(dv * acc[m][3]);
            *(uint2*)(Out + (size_t)gr * 64 + ct) = pk.u;
        }
    }
}

// -------- 2-node edge-aggregation core (pre-scaled fp16 payload) ------------------------
// Each wave aggregates TWO independent nodes (A, B): both nodes' round-A col loads issue
// first (8 loads), then both row batches (up to 32 independent 128B rows in flight).
// wave = 4 groups x 16 lanes; lane l covers channels 4(l&15)..+3.
// Self-loop A handled by group 0, self-loop B by group 1 (summed in the xor-reduce).

#define ACCUM4(ACC, W_, U_) do { \
    union { uint2 u; __half h[4]; } _v; _v.u = (U_); \
    ACC.x = fmaf((W_), __half2float(_v.h[0]), ACC.x); \
    ACC.y = fmaf((W_), __half2float(_v.h[1]), ACC.y); \
    ACC.z = fmaf((W_), __half2float(_v.h[2]), ACC.z); \
    ACC.w = fmaf((W_), __half2float(_v.h[3]), ACC.w); } while (0)

__device__ __forceinline__ void agg_tail(const __half* __restrict__ Hin,
                                         const int* __restrict__ col,
                                         int beg, int end, int g, int l, float4& acc) {
    // edges beyond the first 16 (rare: deg>16), 16 per round
    int e = beg + 16;
    for (; e + 16 <= end; e += 16) {
        int s[4];
#pragma unroll
        for (int k = 0; k < 4; ++k) s[k] = col[e + g + 4 * k];
        uint2 vv[4];
#pragma unroll
        for (int k = 0; k < 4; ++k) vv[k] = *(const uint2*)(Hin + (size_t)s[k] * 64 + l * 4);
#pragma unroll
        for (int k = 0; k < 4; ++k) ACCUM4(acc, 1.f, vv[k]);
    }
    if (e < end) {
        float w[4];
        uint2 vv[4];
#pragma unroll
        for (int k = 0; k < 4; ++k) {
            int ie = e + g + 4 * k;
            int s = (ie < end) ? col[ie] : 0;
            w[k] = (ie < end) ? 1.f : 0.f;
            vv[k] = *(const uint2*)(Hin + (size_t)s * 64 + l * 4);
        }
#pragma unroll
        for (int k = 0; k < 4; ++k) ACCUM4(acc, w[k], vv[k]);
    }
}

__device__ __forceinline__ void agg2_nodes(const __half* __restrict__ Hin,
                                           const int* __restrict__ col,
                                           int iA, int begA, int endA,
                                           int iB, int begB, int endB, bool hasB,
                                           int g, int l, float4& rA, float4& rB) {
    float4 aA = make_float4(0.f, 0.f, 0.f, 0.f);
    float4 aB = make_float4(0.f, 0.f, 0.f, 0.f);
    // round-A col indices for both nodes (8 independent loads)
    int sA[4], sB[4];
    float wA[4], wB[4];
#pragma unroll
    for (int k = 0; k < 4; ++k) {
        int ie = begA + g + 4 * k;
        sA[k] = (ie < endA) ? col[ie] : 0;
        wA[k] = (ie < endA) ? 1.f : 0.f;
    }
#pragma unroll
    for (int k = 0; k < 4; ++k) {
        int ie = begB + g + 4 * k;
        sB[k] = (hasB && ie < endB) ? col[ie] : 0;
        wB[k] = (hasB && ie < endB) ? 1.f : 0.f;
    }
    // self-loops: group 0 carries A's, group 1 carries B's
    uint2 selfu = make_uint2(0, 0);
    if (g == 0) selfu = *(const uint2*)(Hin + (size_t)iA * 64 + l * 4);
    if (g == 1 && hasB) selfu = *(const uint2*)(Hin + (size_t)iB * 64 + l * 4);
    // both row batches: up to 32 independent rows in flight
    uint2 vA[4], vB[4];
#pragma unroll
    for (int k = 0; k < 4; ++k) vA[k] = *(const uint2*)(Hin + (size_t)sA[k] * 64 + l * 4);
#pragma unroll
    for (int k = 0; k < 4; ++k) vB[k] = *(const uint2*)(Hin + (size_t)sB[k] * 64 + l * 4);

    if (g == 0) ACCUM4(aA, 1.f, selfu);
    if (g == 1 && hasB) ACCUM4(aB, 1.f, selfu);
#pragma unroll
    for (int k = 0; k < 4; ++k) ACCUM4(aA, wA[k], vA[k]);
#pragma unroll
    for (int k = 0; k < 4; ++k) ACCUM4(aB, wB[k], vB[k]);

    if (endA - begA > 16) agg_tail(Hin, col, begA, endA, g, l, aA);
    if (hasB && endB - begB > 16) agg_tail(Hin, col, begB, endB, g, l, aB);

    aA.x += __shfl_xor(aA.x, 16); aA.y += __shfl_xor(aA.y, 16);
    aA.z += __shfl_xor(aA.z, 16); aA.w += __shfl_xor(aA.w, 16);
    aA.x += __shfl_xor(aA.x, 32); aA.y += __shfl_xor(aA.y, 32);
    aA.z += __shfl_xor(aA.z, 32); aA.w += __shfl_xor(aA.w, 32);
    aB.x += __shfl_xor(aB.x, 16); aB.y += __shfl_xor(aB.y, 16);
    aB.z += __shfl_xor(aB.z, 16); aB.w += __shfl_xor(aB.w, 16);
    aB.x += __shfl_xor(aB.x, 32); aB.y += __shfl_xor(aB.y, 32);
    aB.z += __shfl_xor(aB.z, 32); aB.w += __shfl_xor(aB.w, 32);
    rA = aA; rB = aB;
}

// layer 1: t = relu(agg + b0); store pre-scaled h' = dinv_i * t   (fp16)
__global__ __launch_bounds__(256, 4) void agg_relu_kernel(
        const __half* __restrict__ Hin, const int* __restrict__ row_ptr,
        const int* __restrict__ col, const float* __restrict__ dinv,
        const float* __restrict__ bias, __half* __restrict__ Hout, int N) {
    int t = threadIdx.x;
    int lane = t & 63;
    int g = lane >> 4, l = lane & 15;
    int gw = (blockIdx.x * blockDim.x + t) >> 6;
    int TW = (gridDim.x * blockDim.x) >> 6;
    int PH = (N + 1) >> 1;

    float4 b4 = (l < 16) ? *(const float4*)(bias + l * 4) : make_float4(0, 0, 0, 0);

    for (int j = gw; j < PH; j += TW) {
        int iA = j, iB = j + PH;
        bool hasB = iB < N;
        int begA = row_ptr[iA], endA = row_ptr[iA + 1];
        int begB = 0, endB = 0;
        if (hasB) { begB = row_ptr[iB]; endB = row_ptr[iB + 1]; }

        float4 rA, rB;
        agg2_nodes(Hin, col, iA, begA, endA, iB, begB, endB, hasB, g, l, rA, rB);

        float dA = dinv[iA];
        if (lane < 16) {
            union { uint2 u; __half h[4]; } pk;
            pk.h[0] = __float2half(dA * fmaxf(dA * rA.x + b4.x, 0.f));
            pk.h[1] = __float2half(dA * fmaxf(dA * rA.y + b4.y, 0.f));
            pk.h[2] = __float2half(dA * fmaxf(dA * rA.z + b4.z, 0.f));
            pk.h[3] = __float2half(dA * fmaxf(dA * rA.w + b4.w, 0.f));
            *(uint2*)(Hout + (size_t)iA * 64 + l * 4) = pk.u;
        }
        if (hasB) {
            float dB = dinv[iB];
            if (lane < 16) {
                union { uint2 u; __half h[4]; } pk;
                pk.h[0] = __float2half(dB * fmaxf(dB * rB.x + b4.x, 0.f));
                pk.h[1] = __float2half(dB * fmaxf(dB * rB.y + b4.y, 0.f));
                pk.h[2] = __float2half(dB * fmaxf(dB * rB.z + b4.z, 0.f));
                pk.h[3] = __float2half(dB * fmaxf(dB * rB.w + b4.w, 0.f));
                *(uint2*)(Hout + (size_t)iB * 64 + l * 4) = pk.u;
            }
        }
    }
}

// layer 2 FUSED: g = agg(h); out = [ g@Wm + bm | g@Wl + bl ]  (agg(h@W) == agg(h)@W)
__global__ __launch_bounds__(256, 4) void agg_out_fused_kernel(
        const __half* __restrict__ Hin, const int* __restrict__ row_ptr,
        const int* __restrict__ col, const float* __restrict__ dinv,
        const float* __restrict__ Wm, const float* __restrict__ Wl,
        const float* __restrict__ bm, const float* __restrict__ bl,
        float* __restrict__ out, int N) {
    __shared__ float Ws[64][64];
    int t = threadIdx.x;
    for (int i = t * 4; i < 64 * 32; i += 1024) {
        int k = i >> 5, c = i & 31;
        *(float4*)&Ws[k][c]      = *(const float4*)(Wm + i);
        *(float4*)&Ws[k][32 + c] = *(const float4*)(Wl + i);
    }
    __syncthreads();

    int lane = t & 63;
    int g = lane >> 4, l = lane & 15;
    float bj = (lane < 32) ? bm[lane] : bl[lane - 32];

    int gw = (blockIdx.x * blockDim.x + t) >> 6;
    int TW = (gridDim.x * blockDim.x) >> 6;
    int PH = (N + 1) >> 1;

    for (int j = gw; j < PH; j += TW) {
        int iA = j, iB = j + PH;
        bool hasB = iB < N;
        int begA = row_ptr[iA], endA = row_ptr[iA + 1];
        int begB = 0, endB = 0;
        if (hasB) { begB = row_ptr[iB]; endB = row_ptr[iB + 1]; }

        float4 rA, rB;
        agg2_nodes(Hin, col, iA, begA, endA, iB, begB, endB, hasB, g, l, rA, rB);

        float dA = dinv[iA];
        float dB = hasB ? dinv[iB] : 0.f;
        float aA[4] = {dA * rA.x, dA * rA.y, dA * rA.z, dA * rA.w};
        float aB[4] = {dB * rB.x, dB * rB.y, dB * rB.z, dB * rB.w};
        float oA0 = bj, oA1 = 0.f, oA2 = 0.f, oA3 = 0.f;
        float oB0 = bj, oB1 = 0.f, oB2 = 0.f, oB3 = 0.f;
#pragma unroll
        for (int k = 0; k < 64; k += 4) {
            int srcl = k >> 2;
            float w0 = Ws[k + 0][lane], w1 = Ws[k + 1][lane];
            float w2 = Ws[k + 2][lane], w3 = Ws[k + 3][lane];
            oA0 = fmaf(__shfl(aA[0], srcl, 64), w0, oA0);
            oA1 = fmaf(__shfl(aA[1], srcl, 64), w1, oA1);
            oA2 = fmaf(__shfl(aA[2], srcl, 64), w2, oA2);
            oA3 = fmaf(__shfl(aA[3], srcl, 64), w3, oA3);
            oB0 = fmaf(__shfl(aB[0], srcl, 64), w0, oB0);
            oB1 = fmaf(__shfl(aB[1], srcl, 64), w1, oB1);
            oB2 = fmaf(__shfl(aB[2], srcl, 64), w2, oB2);
            oB3 = fmaf(__shfl(aB[3], srcl, 64), w3, oB3);
        }
        float oA = (oA0 + oA1) + (oA2 + oA3);
        float oB = (oB0 + oB1) + (oB2 + oB3);
        if (lane < 32) out[(size_t)iA * 32 + lane] = oA;
        else           out[(size_t)(N + iA) * 32 + (lane - 32)] = oA;
        if (hasB) {
            if (lane < 32) out[(size_t)iB * 32 + lane] = oB;
            else           out[(size_t)(N + iB) * 32 + (lane - 32)] = oB;
        }
    }
}

// ---------------- launch ----------------

extern "C" void kernel_launch(void* const* d_in, const int* in_sizes, int n_in,
                              void* d_out, int out_size, void* d_ws, size_t ws_size,
                              hipStream_t stream) {
    const float* x  = (const float*)d_in[0];
    const int*   ei = (const int*)d_in[1];   // int32 (JAX default int)
    const float* W0 = (const float*)d_in[2];
    const float* b0 = (const float*)d_in[3];
    const float* Wm = (const float*)d_in[4];
    const float* bm = (const float*)d_in[5];
    const float* Wl = (const float*)d_in[6];
    const float* bl = (const float*)d_in[7];
    float* out = (float*)d_out;

    int N = in_sizes[0] / 128;
    int E = in_sizes[1] / 2;
    const int* src = ei;
    const int* dst = ei + E;

    char* p = (char*)d_ws;
    auto carve = [&](size_t bytes) -> void* {
        void* q = (void*)p;
        p += (bytes + 255) & ~(size_t)255;
        return q;
    };
    int*    count    = (int*)carve((size_t)N * 4);
    int*    row_ptr  = (int*)carve(((size_t)N + 1) * 4);
    int*    col      = (int*)carve((size_t)E * 4);
    int*    rank     = (int*)carve((size_t)E * 4);
    float*  dinv     = (float*)carve((size_t)N * 4);
    int*    partials = (int*)carve(128 * 4);
    __half* h0       = (__half*)carve((size_t)N * 64 * 2);  // dinv*(x@W0) (fp16)
    __half* h        = (__half*)carve((size_t)N * 64 * 2);  // dinv*relu'd hidden (fp16)

    int nb = (N + 1023) / 1024;  // scan blocks (<=128 for N<=131072)

    hipMemsetAsync(count, 0, (size_t)N * 4, stream);
    hist_rank_kernel<<<2048, 256, 0, stream>>>(dst, E, count, rank);
    scan_partial_kernel<<<nb, 256, 0, stream>>>(count, partials, N);
    scan_top_kernel<<<1, 128, 0, stream>>>(partials, nb, row_ptr, N);
    scan_apply_kernel<<<nb, 256, 0, stream>>>(count, partials, row_ptr, dinv, N);
    scatter_kernel<<<2048, 256, 0, stream>>>(src, dst, rank, E, row_ptr, col, N);

    // layer 0: h0' = dinv * (x @ W0) ; h' = dinv * relu(agg(h0') + b0)
    gemm_kernel<<<(N + 63) / 64, 256, 0, stream>>>(x, W0, dinv, h0, N);
    agg_relu_kernel<<<4096, 256, 0, stream>>>(h0, row_ptr, col, dinv, b0, h, N);

    // layer 2 fused: out = [agg(h')@Wm + bm | agg(h')@Wl + bl]
    agg_out_fused_kernel<<<4096, 256, 0, stream>>>(h, row_ptr, col, dinv, Wm, Wl, bm, bl, out, N);
}

// Round 13
// 288.478 us; speedup vs baseline: 1.8450x; 1.2855x over previous
//
#include <hip/hip_runtime.h>
#include <hip/hip_fp16.h>

// ---------------- preprocessing: histogram+rank, padded 3-phase scan (+dinv), fill, scatter

#define PAD16(c) (((c) + 15) & ~15)

__global__ void hist_rank_kernel(const int* __restrict__ dst, int E, int* __restrict__ count,
                                 int* __restrict__ rank) {
    int stride = gridDim.x * blockDim.x;
    int t = blockIdx.x * blockDim.x + threadIdx.x;
    int E4 = E >> 2;
    for (int e = t; e < E4; e += stride) {
        int4 d = ((const int4*)dst)[e];
        int4 r;
        r.x = atomicAdd(&count[d.x], 1);
        r.y = atomicAdd(&count[d.y], 1);
        r.z = atomicAdd(&count[d.z], 1);
        r.w = atomicAdd(&count[d.w], 1);
        ((int4*)rank)[e] = r;
    }
    for (int e = (E4 << 2) + t; e < E; e += stride) rank[e] = atomicAdd(&count[dst[e]], 1);
}

// phase 1: per-block partial sums of PADDED degrees
__global__ void scan_partial_kernel(const int* __restrict__ count, int* __restrict__ partials,
                                    int N) {
    __shared__ int red[4];
    int t = threadIdx.x;
    int idx = blockIdx.x * 1024 + t * 4;
    int s = 0;
    if (idx + 3 < N) {
        int4 c = *(const int4*)(count + idx);
        s = PAD16(c.x) + PAD16(c.y) + PAD16(c.z) + PAD16(c.w);
    } else {
#pragma unroll
        for (int k = 0; k < 4; ++k)
            if (idx + k < N) s += PAD16(count[idx + k]);
    }
#pragma unroll
    for (int off = 1; off < 64; off <<= 1) s += __shfl_xor(s, off);
    if ((t & 63) == 0) red[t >> 6] = s;
    __syncthreads();
    if (t == 0) partials[blockIdx.x] = red[0] + red[1] + red[2] + red[3];
}

__global__ void scan_top_kernel(int* __restrict__ partials, int nb, int* __restrict__ row_ptr,
                                int N) {
    __shared__ int buf[2][128];
    int t = threadIdx.x;
    buf[0][t] = (t < nb) ? partials[t] : 0;
    __syncthreads();
    int pi = 0;
    for (int off = 1; off < 128; off <<= 1) {
        int v = buf[pi][t];
        if (t >= off) v += buf[pi][t - off];
        buf[pi ^ 1][t] = v;
        pi ^= 1;
        __syncthreads();
    }
    if (t < nb) partials[t] = (t == 0) ? 0 : buf[pi][t - 1];
    if (t == 0) row_ptr[N] = buf[pi][127];
}

// phase 3: padded exclusive scan -> row_ptr ; dinv from REAL degree
__global__ void scan_apply_kernel(const int* __restrict__ count, const int* __restrict__ partials,
                                  int* __restrict__ row_ptr, float* __restrict__ dinv, int N) {
    __shared__ int wsum[4];
    int t = threadIdx.x;
    int idx = blockIdx.x * 1024 + t * 4;
    int4 c = make_int4(0, 0, 0, 0);
    if (idx + 3 < N) {
        c = *(const int4*)(count + idx);
    } else {
        if (idx + 0 < N) c.x = count[idx + 0];
        if (idx + 1 < N) c.y = count[idx + 1];
        if (idx + 2 < N) c.z = count[idx + 2];
    }
    int px = PAD16(c.x), py = PAD16(c.y), pz = PAD16(c.z), pw = PAD16(c.w);
    int s = px + py + pz + pw;
    int incl = s;
#pragma unroll
    for (int off = 1; off < 64; off <<= 1) {
        int v = __shfl_up(incl, off);
        if ((t & 63) >= off) incl += v;
    }
    int wexcl = incl - s;
    int w = t >> 6;
    if ((t & 63) == 63) wsum[w] = incl;
    __syncthreads();
    int base = partials[blockIdx.x] + wexcl;
    for (int k = 0; k < w; ++k) base += wsum[k];
    if (idx + 0 < N) { row_ptr[idx + 0] = base;                dinv[idx + 0] = rsqrtf((float)c.x + 1.f); }
    if (idx + 1 < N) { row_ptr[idx + 1] = base + px;           dinv[idx + 1] = rsqrtf((float)c.y + 1.f); }
    if (idx + 2 < N) { row_ptr[idx + 2] = base + px + py;      dinv[idx + 2] = rsqrtf((float)c.z + 1.f); }
    if (idx + 3 < N) { row_ptr[idx + 3] = base + px + py + pz; dinv[idx + 3] = rsqrtf((float)c.w + 1.f); }
}

// fill padded col with dummy node N; zero the dummy feature rows of h0 and h
__global__ void fill_pad_kernel(int* __restrict__ col, const int* __restrict__ row_ptr, int N,
                                __half* __restrict__ h0, __half* __restrict__ h) {
    int total = row_ptr[N];
    int stride = gridDim.x * blockDim.x;
    for (int t = blockIdx.x * blockDim.x + threadIdx.x; t < total; t += stride) col[t] = N;
    if (blockIdx.x == 0 && threadIdx.x < 64) {
        h0[(size_t)N * 64 + threadIdx.x] = __float2half(0.f);
        h[(size_t)N * 64 + threadIdx.x] = __float2half(0.f);
    }
}

// atomic-free scatter with dst-range write blocking
#define NPASS 8
__global__ void scatter_kernel(const int* __restrict__ src, const int* __restrict__ dst,
                               const int* __restrict__ rank, int E,
                               const int* __restrict__ row_ptr, int* __restrict__ col, int N) {
    int chunk = (N + NPASS - 1) / NPASS;
    int stride = gridDim.x * blockDim.x;
    int t = blockIdx.x * blockDim.x + threadIdx.x;
    int E4 = E >> 2;
    for (int pass = 0; pass < NPASS; ++pass) {
        int lo = pass * chunk, hi = min(lo + chunk, N);
        for (int e = t; e < E4; e += stride) {
            int4 d = ((const int4*)dst)[e];
            int4 s = ((const int4*)src)[e];
            int4 r = ((const int4*)rank)[e];
            if (d.x >= lo && d.x < hi) col[row_ptr[d.x] + r.x] = s.x;
            if (d.y >= lo && d.y < hi) col[row_ptr[d.y] + r.y] = s.y;
            if (d.z >= lo && d.z < hi) col[row_ptr[d.z] + r.z] = s.z;
            if (d.w >= lo && d.w < hi) col[row_ptr[d.w] + r.w] = s.w;
        }
        for (int e = (E4 << 2) + t; e < E; e += stride) {
            int d = dst[e];
            if (d >= lo && d < hi) col[row_ptr[d] + rank[e]] = src[e];
        }
    }
}

// -------- fp32 GEMM, PRE-SCALED fp16 output: Out[r] = dinv[r] * (A @ W)[r] --------------

__global__ __launch_bounds__(256, 2) void gemm_kernel(const float* __restrict__ A,
                                                      const float* __restrict__ W,
                                                      const float* __restrict__ dinv,
                                                      __half* __restrict__ Out, int M) {
    const int K = 128;
    __shared__ float Ws[K][64];
    __shared__ float As[64][68];
    int t = threadIdx.x;
    for (int i = t * 4; i < K * 64; i += 1024)
        *(float4*)&Ws[i >> 6][i & 63] = *(const float4*)(W + i);

    int row0 = blockIdx.x * 64;
    int rt = (t >> 4) * 4;
    int ct = (t & 15) * 4;
    float acc[4][4];
#pragma unroll
    for (int m = 0; m < 4; m++) { acc[m][0] = 0.f; acc[m][1] = 0.f; acc[m][2] = 0.f; acc[m][3] = 0.f; }

    for (int k0 = 0; k0 < K; k0 += 64) {
        __syncthreads();
        for (int i = t * 4; i < 64 * 64; i += 1024) {
            int r = i >> 6, c = i & 63;
            int gr = row0 + r;
            float4 v = make_float4(0.f, 0.f, 0.f, 0.f);
            if (gr < M) v = *(const float4*)(A + (size_t)gr * K + k0 + c);
            *(float4*)&As[r][c] = v;
        }
        __syncthreads();
#pragma unroll
        for (int kk = 0; kk < 64; ++kk) {
            float a0 = As[rt + 0][kk], a1 = As[rt + 1][kk];
            float a2 = As[rt + 2][kk], a3 = As[rt + 3][kk];
            float4 w = *(float4*)&Ws[k0 + kk][ct];
            acc[0][0] += a0 * w.x; acc[0][1] += a0 * w.y; acc[0][2] += a0 * w.z; acc[0][3] += a0 * w.w;
            acc[1][0] += a1 * w.x; acc[1][1] += a1 * w.y; acc[1][2] += a1 * w.z; acc[1][3] += a1 * w.w;
            acc[2][0] += a2 * w.x; acc[2][1] += a2 * w.y; acc[2][2] += a2 * w.z; acc[2][3] += a2 * w.w;
            acc[3][0] += a3 * w.x; acc[3][1] += a3 * w.y; acc[3][2] += a3 * w.z; acc[3][3] += a3 * w.w;
        }
    }
#pragma unroll
    for (int m = 0; m < 4; m++) {
        int gr = row0 + rt + m;
        if (gr < M) {
            float dv = dinv[gr];
            union { uint2 u; __half h[4]; } pk;
            pk.h[0] = __float2half(dv * acc[m][0]);
            pk.h[1] = __float2half(dv * acc[m][1]);
            pk.h[2] = __float2half(dv * acc[m][2]);
            pk.h[3] = __float2half(dv * acc[m][3]);
            *(uint2*)(Out + (size_t)gr * 64 + ct) = pk.u;
        }
    }
}

// -------- wide-load edge-aggregation core (pre-scaled fp16 payload, padded CSR) ----------
// wave = 8 groups x 8 lanes. lane l = lane&7 covers channels 8l..8l+7 (uint4 = 8 halves =
// 16B/lane, 8 lanes/row -> ONE load instruction covers 8 rows). Edge list padded to a
// multiple of 16 with dummy node N (zero row): single unpredicated round covers deg<=16.

typedef union { uint4 u; __half h[8]; } h8_t;

#define ACC8(A_, U_) do { h8_t _v; _v.u = (U_); \
    A_[0] += __half2float(_v.h[0]); A_[1] += __half2float(_v.h[1]); \
    A_[2] += __half2float(_v.h[2]); A_[3] += __half2float(_v.h[3]); \
    A_[4] += __half2float(_v.h[4]); A_[5] += __half2float(_v.h[5]); \
    A_[6] += __half2float(_v.h[6]); A_[7] += __half2float(_v.h[7]); } while (0)

__device__ __forceinline__ void agg_node_w(const __half* __restrict__ Hin,
                                           const int* __restrict__ col,
                                           int i, int beg, int end, int g, int l,
                                           float* a /*[8]*/) {
#pragma unroll
    for (int j = 0; j < 8; ++j) a[j] = 0.f;
    if (g == 0) {  // self-loop (pre-scaled h'_i)
        uint4 sv = *(const uint4*)(Hin + (size_t)i * 64 + l * 8);
        ACC8(a, sv);
    }
    for (int e = beg; e < end; e += 16) {  // always full rounds (padded)
        int s0 = col[e + g];
        int s1 = col[e + g + 8];
        uint4 v0 = *(const uint4*)(Hin + (size_t)s0 * 64 + l * 8);
        uint4 v1 = *(const uint4*)(Hin + (size_t)s1 * 64 + l * 8);
        ACC8(a, v0);
        ACC8(a, v1);
    }
    // reduce across the 8 groups (lane bits 3,4,5)
#pragma unroll
    for (int j = 0; j < 8; ++j) {
        a[j] += __shfl_xor(a[j], 8);
        a[j] += __shfl_xor(a[j], 16);
        a[j] += __shfl_xor(a[j], 32);
    }
}

// layer 1: t = relu(di*agg + b0); store pre-scaled h' = di * t   (fp16)
__global__ __launch_bounds__(256, 4) void agg_relu_kernel(
        const __half* __restrict__ Hin, const int* __restrict__ row_ptr,
        const int* __restrict__ col, const float* __restrict__ dinv,
        const float* __restrict__ bias, __half* __restrict__ Hout, int N) {
    int t = threadIdx.x;
    int lane = t & 63;
    int g = lane >> 3, l = lane & 7;
    int gw = (blockIdx.x * blockDim.x + t) >> 6;
    int TW = (gridDim.x * blockDim.x) >> 6;

    float b8[8];
    if (lane < 8) {
        float4 u = *(const float4*)(bias + lane * 8);
        float4 v = *(const float4*)(bias + lane * 8 + 4);
        b8[0] = u.x; b8[1] = u.y; b8[2] = u.z; b8[3] = u.w;
        b8[4] = v.x; b8[5] = v.y; b8[6] = v.z; b8[7] = v.w;
    }

    for (int i = gw; i < N; i += TW) {
        int beg = row_ptr[i], end = row_ptr[i + 1];
        float di = dinv[i];
        float a[8];
        agg_node_w(Hin, col, i, beg, end, g, l, a);
        if (lane < 8) {
            h8_t pk;
#pragma unroll
            for (int j = 0; j < 8; ++j)
                pk.h[j] = __float2half(di * fmaxf(di * a[j] + b8[j], 0.f));
            *(uint4*)(Hout + (size_t)i * 64 + lane * 8) = pk.u;
        }
    }
}

// layer 2 FUSED: gvec = di*agg(h'); out = [ gvec@Wm + bm | gvec@Wl + bl ]
__global__ __launch_bounds__(256, 4) void agg_out_fused_kernel(
        const __half* __restrict__ Hin, const int* __restrict__ row_ptr,
        const int* __restrict__ col, const float* __restrict__ dinv,
        const float* __restrict__ Wm, const float* __restrict__ Wl,
        const float* __restrict__ bm, const float* __restrict__ bl,
        float* __restrict__ out, int N) {
    __shared__ float Ws[64][64];
    int t = threadIdx.x;
    for (int i = t * 4; i < 64 * 32; i += 1024) {
        int k = i >> 5, c = i & 31;
        *(float4*)&Ws[k][c]      = *(const float4*)(Wm + i);
        *(float4*)&Ws[k][32 + c] = *(const float4*)(Wl + i);
    }
    __syncthreads();

    int lane = t & 63;
    int g = lane >> 3, l = lane & 7;
    float bj = (lane < 32) ? bm[lane] : bl[lane - 32];

    int gw = (blockIdx.x * blockDim.x + t) >> 6;
    int TW = (gridDim.x * blockDim.x) >> 6;

    for (int i = gw; i < N; i += TW) {
        int beg = row_ptr[i], end = row_ptr[i + 1];
        float di = dinv[i];
        float a[8];
        agg_node_w(Hin, col, i, beg, end, g, l, a);
#pragma unroll
        for (int j = 0; j < 8; ++j) a[j] *= di;
        // out[j] = sum_k gvec[k]*Ws[k][j] + b[j]; gvec[k] lives in lane (k>>3), comp (k&7)
        float o0 = bj, o1 = 0.f, o2 = 0.f, o3 = 0.f;
#pragma unroll
        for (int k = 0; k < 64; k += 4) {
            o0 = fmaf(__shfl(a[(k + 0) & 7], (k + 0) >> 3, 64), Ws[k + 0][lane], o0);
            o1 = fmaf(__shfl(a[(k + 1) & 7], (k + 1) >> 3, 64), Ws[k + 1][lane], o1);
            o2 = fmaf(__shfl(a[(k + 2) & 7], (k + 2) >> 3, 64), Ws[k + 2][lane], o2);
            o3 = fmaf(__shfl(a[(k + 3) & 7], (k + 3) >> 3, 64), Ws[k + 3][lane], o3);
        }
        float o = (o0 + o1) + (o2 + o3);
        if (lane < 32) out[(size_t)i * 32 + lane] = o;
        else           out[(size_t)(N + i) * 32 + (lane - 32)] = o;
    }
}

// ---------------- launch ----------------

extern "C" void kernel_launch(void* const* d_in, const int* in_sizes, int n_in,
                              void* d_out, int out_size, void* d_ws, size_t ws_size,
                              hipStream_t stream) {
    const float* x  = (const float*)d_in[0];
    const int*   ei = (const int*)d_in[1];   // int32 (JAX default int)
    const float* W0 = (const float*)d_in[2];
    const float* b0 = (const float*)d_in[3];
    const float* Wm = (const float*)d_in[4];
    const float* bm = (const float*)d_in[5];
    const float* Wl = (const float*)d_in[6];
    const float* bl = (const float*)d_in[7];
    float* out = (float*)d_out;

    int N = in_sizes[0] / 128;
    int E = in_sizes[1] / 2;
    const int* src = ei;
    const int* dst = ei + E;

    char* p = (char*)d_ws;
    auto carve = [&](size_t bytes) -> void* {
        void* q = (void*)p;
        p += (bytes + 255) & ~(size_t)255;
        return q;
    };
    size_t colCap = (size_t)E + 15 * (size_t)N + 16;        // padded upper bound
    int*    count    = (int*)carve((size_t)N * 4);
    int*    row_ptr  = (int*)carve(((size_t)N + 1) * 4);
    int*    col      = (int*)carve(colCap * 4);
    int*    rank     = (int*)carve((size_t)E * 4);
    float*  dinv     = (float*)carve((size_t)N * 4);
    int*    partials = (int*)carve(128 * 4);
    __half* h0       = (__half*)carve(((size_t)N + 1) * 64 * 2);  // dinv*(x@W0), +dummy row
    __half* h        = (__half*)carve(((size_t)N + 1) * 64 * 2);  // dinv*relu hidden, +dummy

    int nb = (N + 1023) / 1024;  // scan blocks (<=128 for N<=131072)

    hipMemsetAsync(count, 0, (size_t)N * 4, stream);
    hist_rank_kernel<<<2048, 256, 0, stream>>>(dst, E, count, rank);
    scan_partial_kernel<<<nb, 256, 0, stream>>>(count, partials, N);
    scan_top_kernel<<<1, 128, 0, stream>>>(partials, nb, row_ptr, N);
    scan_apply_kernel<<<nb, 256, 0, stream>>>(count, partials, row_ptr, dinv, N);
    fill_pad_kernel<<<2048, 256, 0, stream>>>(col, row_ptr, N, h0, h);
    scatter_kernel<<<2048, 256, 0, stream>>>(src, dst, rank, E, row_ptr, col, N);

    // layer 0: h0' = dinv * (x @ W0) ; h' = dinv * relu(agg(h0') + b0)
    gemm_kernel<<<(N + 63) / 64, 256, 0, stream>>>(x, W0, dinv, h0, N);
    agg_relu_kernel<<<4096, 256, 0, stream>>>(h0, row_ptr, col, dinv, b0, h, N);

    // layer 2 fused: out = [agg(h')@Wm + bm | agg(h')@Wl + bl]
    agg_out_fused_kernel<<<4096, 256, 0, stream>>>(h, row_ptr, col, dinv, Wm, Wl, bm, bl, out, N);
}

// Round 14
// 273.242 us; speedup vs baseline: 1.9479x; 1.0558x over previous
//
#include <hip/hip_runtime.h>
#include <hip/hip_fp16.h>

// ---------------- preprocessing: histogram+rank, 3-phase scan (+dinv), passed scatter ----

__global__ void hist_rank_kernel(const int* __restrict__ dst, int E, int* __restrict__ count,
                                 int* __restrict__ rank) {
    int stride = gridDim.x * blockDim.x;
    int t = blockIdx.x * blockDim.x + threadIdx.x;
    int E4 = E >> 2;
    for (int e = t; e < E4; e += stride) {
        int4 d = ((const int4*)dst)[e];
        int4 r;
        r.x = atomicAdd(&count[d.x], 1);
        r.y = atomicAdd(&count[d.y], 1);
        r.z = atomicAdd(&count[d.z], 1);
        r.w = atomicAdd(&count[d.w], 1);
        ((int4*)rank)[e] = r;
    }
    for (int e = (E4 << 2) + t; e < E; e += stride) rank[e] = atomicAdd(&count[dst[e]], 1);
}

__global__ void scan_partial_kernel(const int* __restrict__ count, int* __restrict__ partials,
                                    int N) {
    __shared__ int red[4];
    int t = threadIdx.x;
    int idx = blockIdx.x * 1024 + t * 4;
    int s = 0;
    if (idx + 3 < N) {
        int4 c = *(const int4*)(count + idx);
        s = c.x + c.y + c.z + c.w;
    } else {
#pragma unroll
        for (int k = 0; k < 4; ++k)
            if (idx + k < N) s += count[idx + k];
    }
#pragma unroll
    for (int off = 1; off < 64; off <<= 1) s += __shfl_xor(s, off);
    if ((t & 63) == 0) red[t >> 6] = s;
    __syncthreads();
    if (t == 0) partials[blockIdx.x] = red[0] + red[1] + red[2] + red[3];
}

__global__ void scan_top_kernel(int* __restrict__ partials, int nb, int* __restrict__ row_ptr,
                                int N) {
    __shared__ int buf[2][128];
    int t = threadIdx.x;
    buf[0][t] = (t < nb) ? partials[t] : 0;
    __syncthreads();
    int pi = 0;
    for (int off = 1; off < 128; off <<= 1) {
        int v = buf[pi][t];
        if (t >= off) v += buf[pi][t - off];
        buf[pi ^ 1][t] = v;
        pi ^= 1;
        __syncthreads();
    }
    if (t < nb) partials[t] = (t == 0) ? 0 : buf[pi][t - 1];
    if (t == 0) row_ptr[N] = buf[pi][127];
}

__global__ void scan_apply_kernel(const int* __restrict__ count, const int* __restrict__ partials,
                                  int* __restrict__ row_ptr, float* __restrict__ dinv, int N) {
    __shared__ int wsum[4];
    int t = threadIdx.x;
    int idx = blockIdx.x * 1024 + t * 4;
    int4 c = make_int4(0, 0, 0, 0);
    if (idx + 3 < N) {
        c = *(const int4*)(count + idx);
    } else {
        if (idx + 0 < N) c.x = count[idx + 0];
        if (idx + 1 < N) c.y = count[idx + 1];
        if (idx + 2 < N) c.z = count[idx + 2];
    }
    int s = c.x + c.y + c.z + c.w;
    int incl = s;
#pragma unroll
    for (int off = 1; off < 64; off <<= 1) {
        int v = __shfl_up(incl, off);
        if ((t & 63) >= off) incl += v;
    }
    int wexcl = incl - s;
    int w = t >> 6;
    if ((t & 63) == 63) wsum[w] = incl;
    __syncthreads();
    int base = partials[blockIdx.x] + wexcl;
    for (int k = 0; k < w; ++k) base += wsum[k];
    if (idx + 0 < N) { row_ptr[idx + 0] = base;                   dinv[idx + 0] = rsqrtf((float)c.x + 1.f); }
    if (idx + 1 < N) { row_ptr[idx + 1] = base + c.x;             dinv[idx + 1] = rsqrtf((float)c.y + 1.f); }
    if (idx + 2 < N) { row_ptr[idx + 2] = base + c.x + c.y;       dinv[idx + 2] = rsqrtf((float)c.z + 1.f); }
    if (idx + 3 < N) { row_ptr[idx + 3] = base + c.x + c.y + c.z; dinv[idx + 3] = rsqrtf((float)c.w + 1.f); }
}

// atomic-free scatter with dst-range write blocking (pass p writes only a ~N/NPASS window)
#define NPASS 8
__global__ void scatter_kernel(const int* __restrict__ src, const int* __restrict__ dst,
                               const int* __restrict__ rank, int E,
                               const int* __restrict__ row_ptr, int* __restrict__ col, int N) {
    int chunk = (N + NPASS - 1) / NPASS;
    int stride = gridDim.x * blockDim.x;
    int t = blockIdx.x * blockDim.x + threadIdx.x;
    int E4 = E >> 2;
    for (int pass = 0; pass < NPASS; ++pass) {
        int lo = pass * chunk, hi = min(lo + chunk, N);
        for (int e = t; e < E4; e += stride) {
            int4 d = ((const int4*)dst)[e];
            int4 s = ((const int4*)src)[e];
            int4 r = ((const int4*)rank)[e];
            if (d.x >= lo && d.x < hi) col[row_ptr[d.x] + r.x] = s.x;
            if (d.y >= lo && d.y < hi) col[row_ptr[d.y] + r.y] = s.y;
            if (d.z >= lo && d.z < hi) col[row_ptr[d.z] + r.z] = s.z;
            if (d.w >= lo && d.w < hi) col[row_ptr[d.w] + r.w] = s.w;
        }
        for (int e = (E4 << 2) + t; e < E; e += stride) {
            int d = dst[e];
            if (d >= lo && d < hi) col[row_ptr[d] + rank[e]] = src[e];
        }
    }
}

// -------- fp32 GEMM, PRE-SCALED fp16 output: Out[r] = dinv[r] * (A @ W)[r] --------------

__global__ __launch_bounds__(256, 2) void gemm_kernel(const float* __restrict__ A,
                                                      const float* __restrict__ W,
                                                      const float* __restrict__ dinv,
                                                      __half* __restrict__ Out, int M) {
    const int K = 128;
    __shared__ float Ws[K][64];
    __shared__ float As[64][68];
    int t = threadIdx.x;
    for (int i = t * 4; i < K * 64; i += 1024)
        *(float4*)&Ws[i >> 6][i & 63] = *(const float4*)(W + i);

    int row0 = blockIdx.x * 64;
    int rt = (t >> 4) * 4;
    int ct = (t & 15) * 4;
    float acc[4][4];
#pragma unroll
    for (int m = 0; m < 4; m++) { acc[m][0] = 0.f; acc[m][1] = 0.f; acc[m][2] = 0.f; acc[m][3] = 0.f; }

    for (int k0 = 0; k0 < K; k0 += 64) {
        __syncthreads();
        for (int i = t * 4; i < 64 * 64; i += 1024) {
            int r = i >> 6, c = i & 63;
            int gr = row0 + r;
            float4 v = make_float4(0.f, 0.f, 0.f, 0.f);
            if (gr < M) v = *(const float4*)(A + (size_t)gr * K + k0 + c);
            *(float4*)&As[r][c] = v;
        }
        __syncthreads();
#pragma unroll
        for (int kk = 0; kk < 64; ++kk) {
            float a0 = As[rt + 0][kk], a1 = As[rt + 1][kk];
            float a2 = As[rt + 2][kk], a3 = As[rt + 3][kk];
            float4 w = *(float4*)&Ws[k0 + kk][ct];
            acc[0][0] += a0 * w.x; acc[0][1] += a0 * w.y; acc[0][2] += a0 * w.z; acc[0][3] += a0 * w.w;
            acc[1][0] += a1 * w.x; acc[1][1] += a1 * w.y; acc[1][2] += a1 * w.z; acc[1][3] += a1 * w.w;
            acc[2][0] += a2 * w.x; acc[2][1] += a2 * w.y; acc[2][2] += a2 * w.z; acc[2][3] += a2 * w.w;
            acc[3][0] += a3 * w.x; acc[3][1] += a3 * w.y; acc[3][2] += a3 * w.z; acc[3][3] += a3 * w.w;
        }
    }
#pragma unroll
    for (int m = 0; m < 4; m++) {
        int gr = row0 + rt + m;
        if (gr < M) {
            float dv = dinv[gr];
            union { uint2 u; __half h[4]; } pk;
            pk.h[0] = __float2half(dv * acc[m][0]);
            pk.h[1] = __float2half(dv * acc[m][1]);
            pk.h[2] = __float2half(dv * acc[m][2]);
            pk.h[3] = __float2half(dv * acc[m][3]);
            *(uint2*)(Out + (size_t)gr * 64 + ct) = pk.u;
        }
    }
}

// -------- pipelined edge-aggregation core (pre-scaled fp16 payload) ---------------------
// wave = 4 groups x 16 lanes; lane l covers channels 4(l&15)..+3.

__device__ __forceinline__ float4 agg_body(const __half* __restrict__ Hin,
                                           const int* __restrict__ col,
                                           const int* pc, int beg, int end,
                                           int i, int g, int l) {
    float4 acc = make_float4(0.f, 0.f, 0.f, 0.f);
    if (g == 0) {  // self-loop (pre-scaled: h'_i)
        union { uint2 u; __half h[4]; } v;
        v.u = *(const uint2*)(Hin + (size_t)i * 64 + l * 4);
        acc.x = __half2float(v.h[0]); acc.y = __half2float(v.h[1]);
        acc.z = __half2float(v.h[2]); acc.w = __half2float(v.h[3]);
    }
    {   // round A: prefetched cols, predicated by weight
        float w[4];
        uint2 vv[4];
#pragma unroll
        for (int k = 0; k < 4; ++k) {
            w[k] = (beg + g + 4 * k < end) ? 1.f : 0.f;
            vv[k] = *(const uint2*)(Hin + (size_t)pc[k] * 64 + l * 4);
        }
#pragma unroll
        for (int k = 0; k < 4; ++k) {
            union { uint2 u; __half h[4]; } v;
            v.u = vv[k];
            acc.x = fmaf(w[k], __half2float(v.h[0]), acc.x);
            acc.y = fmaf(w[k], __half2float(v.h[1]), acc.y);
            acc.z = fmaf(w[k], __half2float(v.h[2]), acc.z);
            acc.w = fmaf(w[k], __half2float(v.h[3]), acc.w);
        }
    }
    // overflow (deg>16): dynamic rounds
    int e = beg + 16;
    for (; e + 16 <= end; e += 16) {
        int s[4];
#pragma unroll
        for (int k = 0; k < 4; ++k) s[k] = col[e + g + 4 * k];
        uint2 vv[4];
#pragma unroll
        for (int k = 0; k < 4; ++k) vv[k] = *(const uint2*)(Hin + (size_t)s[k] * 64 + l * 4);
#pragma unroll
        for (int k = 0; k < 4; ++k) {
            union { uint2 u; __half h[4]; } v;
            v.u = vv[k];
            acc.x += __half2float(v.h[0]); acc.y += __half2float(v.h[1]);
            acc.z += __half2float(v.h[2]); acc.w += __half2float(v.h[3]);
        }
    }
    if (e < end) {
        float w[4];
        uint2 vv[4];
#pragma unroll
        for (int k = 0; k < 4; ++k) {
            int ie = e + g + 4 * k;
            int s = (ie < end) ? col[ie] : 0;
            w[k] = (ie < end) ? 1.f : 0.f;
            vv[k] = *(const uint2*)(Hin + (size_t)s * 64 + l * 4);
        }
#pragma unroll
        for (int k = 0; k < 4; ++k) {
            union { uint2 u; __half h[4]; } v;
            v.u = vv[k];
            acc.x = fmaf(w[k], __half2float(v.h[0]), acc.x);
            acc.y = fmaf(w[k], __half2float(v.h[1]), acc.y);
            acc.z = fmaf(w[k], __half2float(v.h[2]), acc.z);
            acc.w = fmaf(w[k], __half2float(v.h[3]), acc.w);
        }
    }
    acc.x += __shfl_xor(acc.x, 16); acc.y += __shfl_xor(acc.y, 16);
    acc.z += __shfl_xor(acc.z, 16); acc.w += __shfl_xor(acc.w, 16);
    acc.x += __shfl_xor(acc.x, 32); acc.y += __shfl_xor(acc.y, 32);
    acc.z += __shfl_xor(acc.z, 32); acc.w += __shfl_xor(acc.w, 32);
    return acc;
}

// layer 1: t = relu(agg + b0); store pre-scaled h' = dinv_i * t   (fp16)
__global__ __launch_bounds__(256, 4) void agg_relu_kernel(
        const __half* __restrict__ Hin, const int* __restrict__ row_ptr,
        const int* __restrict__ col, const float* __restrict__ dinv,
        const float* __restrict__ bias, __half* __restrict__ Hout, int N) {
    int t = threadIdx.x;
    int lane = t & 63;
    int g = lane >> 4, l = lane & 15;
    int gw = (blockIdx.x * blockDim.x + t) >> 6;
    int TW = (gridDim.x * blockDim.x) >> 6;

    float4 b4 = (l < 16) ? *(const float4*)(bias + l * 4) : make_float4(0, 0, 0, 0);

    int i = gw;
    int beg = 0, end = 0, pc0 = 0, pc1 = 0, pc2 = 0, pc3 = 0;
    if (i < N) {
        beg = row_ptr[i]; end = row_ptr[i + 1];
        pc0 = (beg + g      < end) ? col[beg + g]      : 0;
        pc1 = (beg + g + 4  < end) ? col[beg + g + 4]  : 0;
        pc2 = (beg + g + 8  < end) ? col[beg + g + 8]  : 0;
        pc3 = (beg + g + 12 < end) ? col[beg + g + 12] : 0;
    }
    while (i < N) {
        int inext = i + TW;
        int beg_n = 0, end_n = 0;
        if (inext < N) { beg_n = row_ptr[inext]; end_n = row_ptr[inext + 1]; }

        int pc[4] = {pc0, pc1, pc2, pc3};
        float di = dinv[i];
        float4 r = agg_body(Hin, col, pc, beg, end, i, g, l);

        if (inext < N) {
            pc0 = (beg_n + g      < end_n) ? col[beg_n + g]      : 0;
            pc1 = (beg_n + g + 4  < end_n) ? col[beg_n + g + 4]  : 0;
            pc2 = (beg_n + g + 8  < end_n) ? col[beg_n + g + 8]  : 0;
            pc3 = (beg_n + g + 12 < end_n) ? col[beg_n + g + 12] : 0;
        }

        if (lane < 16) {
            union { uint2 u; __half h[4]; } pk;
            pk.h[0] = __float2half(di * fmaxf(di * r.x + b4.x, 0.f));
            pk.h[1] = __float2half(di * fmaxf(di * r.y + b4.y, 0.f));
            pk.h[2] = __float2half(di * fmaxf(di * r.z + b4.z, 0.f));
            pk.h[3] = __float2half(di * fmaxf(di * r.w + b4.w, 0.f));
            *(uint2*)(Hout + (size_t)i * 64 + l * 4) = pk.u;
        }
        beg = beg_n; end = end_n; i = inext;
    }
}

// layer 2 FUSED: g = agg(h); out = [ g@Wm + bm | g@Wl + bl ]  (agg(h@W) == agg(h)@W)
__global__ __launch_bounds__(256, 4) void agg_out_fused_kernel(
        const __half* __restrict__ Hin, const int* __restrict__ row_ptr,
        const int* __restrict__ col, const float* __restrict__ dinv,
        const float* __restrict__ Wm, const float* __restrict__ Wl,
        const float* __restrict__ bm, const float* __restrict__ bl,
        float* __restrict__ out, int N) {
    __shared__ float Ws[64][64];
    int t = threadIdx.x;
    for (int i = t * 4; i < 64 * 32; i += 1024) {
        int k = i >> 5, c = i & 31;
        *(float4*)&Ws[k][c]      = *(const float4*)(Wm + i);
        *(float4*)&Ws[k][32 + c] = *(const float4*)(Wl + i);
    }
    __syncthreads();

    int lane = t & 63;
    int g = lane >> 4, l = lane & 15;
    float bj = (lane < 32) ? bm[lane] : bl[lane - 32];

    int gw = (blockIdx.x * blockDim.x + t) >> 6;
    int TW = (gridDim.x * blockDim.x) >> 6;

    int i = gw;
    int beg = 0, end = 0, pc0 = 0, pc1 = 0, pc2 = 0, pc3 = 0;
    if (i < N) {
        beg = row_ptr[i]; end = row_ptr[i + 1];
        pc0 = (beg + g      < end) ? col[beg + g]      : 0;
        pc1 = (beg + g + 4  < end) ? col[beg + g + 4]  : 0;
        pc2 = (beg + g + 8  < end) ? col[beg + g + 8]  : 0;
        pc3 = (beg + g + 12 < end) ? col[beg + g + 12] : 0;
    }
    while (i < N) {
        int inext = i + TW;
        int beg_n = 0, end_n = 0;
        if (inext < N) { beg_n = row_ptr[inext]; end_n = row_ptr[inext + 1]; }

        int pc[4] = {pc0, pc1, pc2, pc3};
        float di = dinv[i];
        float4 r = agg_body(Hin, col, pc, beg, end, i, g, l);

        if (inext < N) {
            pc0 = (beg_n + g      < end_n) ? col[beg_n + g]      : 0;
            pc1 = (beg_n + g + 4  < end_n) ? col[beg_n + g + 4]  : 0;
            pc2 = (beg_n + g + 8  < end_n) ? col[beg_n + g + 8]  : 0;
            pc3 = (beg_n + g + 12 < end_n) ? col[beg_n + g + 12] : 0;
        }

        float a[4] = {di * r.x, di * r.y, di * r.z, di * r.w};
        float o0 = bj, o1 = 0.f, o2 = 0.f, o3 = 0.f;
#pragma unroll
        for (int k = 0; k < 64; k += 4) {
            int srcl = k >> 2;
            o0 = fmaf(__shfl(a[0], srcl, 64), Ws[k + 0][lane], o0);
            o1 = fmaf(__shfl(a[1], srcl, 64), Ws[k + 1][lane], o1);
            o2 = fmaf(__shfl(a[2], srcl, 64), Ws[k + 2][lane], o2);
            o3 = fmaf(__shfl(a[3], srcl, 64), Ws[k + 3][lane], o3);
        }
        float o = (o0 + o1) + (o2 + o3);
        if (lane < 32) out[(size_t)i * 32 + lane] = o;
        else           out[(size_t)(N + i) * 32 + (lane - 32)] = o;

        beg = beg_n; end = end_n; i = inext;
    }
}

// ---------------- launch ----------------

extern "C" void kernel_launch(void* const* d_in, const int* in_sizes, int n_in,
                              void* d_out, int out_size, void* d_ws, size_t ws_size,
                              hipStream_t stream) {
    const float* x  = (const float*)d_in[0];
    const int*   ei = (const int*)d_in[1];   // int32 (JAX default int)
    const float* W0 = (const float*)d_in[2];
    const float* b0 = (const float*)d_in[3];
    const float* Wm = (const float*)d_in[4];
    const float* bm = (const float*)d_in[5];
    const float* Wl = (const float*)d_in[6];
    const float* bl = (const float*)d_in[7];
    float* out = (float*)d_out;

    int N = in_sizes[0] / 128;
    int E = in_sizes[1] / 2;
    const int* src = ei;
    const int* dst = ei + E;

    char* p = (char*)d_ws;
    auto carve = [&](size_t bytes) -> void* {
        void* q = (void*)p;
        p += (bytes + 255) & ~(size_t)255;
        return q;
    };
    int*    count    = (int*)carve((size_t)N * 4);
    int*    row_ptr  = (int*)carve(((size_t)N + 1) * 4);
    int*    col      = (int*)carve((size_t)E * 4);
    int*    rank     = (int*)carve((size_t)E * 4);
    float*  dinv     = (float*)carve((size_t)N * 4);
    int*    partials = (int*)carve(128 * 4);
    __half* h0       = (__half*)carve((size_t)N * 64 * 2);  // dinv*(x@W0) (fp16)
    __half* h        = (__half*)carve((size_t)N * 64 * 2);  // dinv*relu'd hidden (fp16)

    int nb = (N + 1023) / 1024;  // scan blocks (<=128 for N<=131072)

    hipMemsetAsync(count, 0, (size_t)N * 4, stream);
    hist_rank_kernel<<<2048, 256, 0, stream>>>(dst, E, count, rank);
    scan_partial_kernel<<<nb, 256, 0, stream>>>(count, partials, N);
    scan_top_kernel<<<1, 128, 0, stream>>>(partials, nb, row_ptr, N);
    scan_apply_kernel<<<nb, 256, 0, stream>>>(count, partials, row_ptr, dinv, N);
    scatter_kernel<<<2048, 256, 0, stream>>>(src, dst, rank, E, row_ptr, col, N);

    // layer 0: h0' = dinv * (x @ W0) ; h' = dinv * relu(agg(h0') + b0)
    gemm_kernel<<<(N + 63) / 64, 256, 0, stream>>>(x, W0, dinv, h0, N);
    agg_relu_kernel<<<2048, 256, 0, stream>>>(h0, row_ptr, col, dinv, b0, h, N);

    // layer 2 fused: out = [agg(h')@Wm + bm | agg(h')@Wl + bl]
    agg_out_fused_kernel<<<2048, 256, 0, stream>>>(h, row_ptr, col, dinv, Wm, Wl, bm, bl, out, N);
}